// Round 9
// baseline (45.089 us; speedup 1.0000x reference)
//
#include <hip/hip_runtime.h>
#include <hip/hip_bf16.h>
#include <hip/hip_fp16.h>
#include <math.h>

#define BB 64
#define CC 3
#define HH 384
#define WW 384
#define HW (HH * WW)

// Each block: 64x24 output tile of one image (3 channels), staged via LDS
// as fp16-packed uint2 texels {h2(c0,c1), h(c2)}. 512 threads = 64(x) x 8(y),
// each thread does 3 rows (stride 8).
#define TILE_W 64
#define TILE_H 24
#define TX_TILES (WW / TILE_W)                 // 6
#define TY_TILES (HH / TILE_H)                 // 16
#define TILES_PER_IMG (TX_TILES * TY_TILES)    // 96
#define NBLOCKS (BB * TILES_PER_IMG)           // 6144 (divisible by 8)

// Rotated bbox of 64x24 at <=15deg: LW <= 71, LH <= 43.
#define LW_STRIDE 71
#define LH_MAX 43
// LDS = 43*71*8 = 24424 B -> 4 blocks/CU x 8 waves = 32 waves (100%)

__device__ __forceinline__ float3 unp(uint2 q) {
    __half2 h01 = *reinterpret_cast<__half2*>(&q.x);
    float2 f01 = __half22float2(h01);
    unsigned short u2 = (unsigned short)(q.y & 0xFFFF);
    __half h2 = *reinterpret_cast<__half*>(&u2);
    return make_float3(f01.x, f01.y, __half2float(h2));
}

__device__ __forceinline__ uint2 pck(float c0, float c1, float c2) {
    __half2 h01 = __floats2half2_rn(c0, c1);
    unsigned int lo = *reinterpret_cast<unsigned int*>(&h01);
    __half h2 = __float2half_rn(c2);
    unsigned int hi = (unsigned int)(*reinterpret_cast<unsigned short*>(&h2));
    return make_uint2(lo, hi);
}

__global__ __launch_bounds__(512, 8) void GeometricAugment_kernel(
    const float* __restrict__ x,
    const float* __restrict__ angles,
    const float* __restrict__ dx,
    const float* __restrict__ dy,
    float* __restrict__ out) {

    __shared__ uint2 ldsT[LH_MAX * LW_STRIDE];

    // XCD-chunked bijective swizzle (6144 % 8 == 0)
    int bid = blockIdx.x;
    int swz = (bid & 7) * (NBLOCKS / 8) + (bid >> 3);

    int b   = swz / TILES_PER_IMG;
    int t   = swz - b * TILES_PER_IMG;
    int tyb = t / TX_TILES;
    int txb = t - tyb * TX_TILES;

    int tid = threadIdx.x;
    int tx  = tid & 63;   // 0..63
    int tyl = tid >> 6;   // 0..7

    const int X0 = txb * TILE_W;
    const int Y0 = tyb * TILE_H;

    const float cx = (WW - 1) * 0.5f;
    const float cy = (HH - 1) * 0.5f;

    float rad = angles[b] * (float)(M_PI / 180.0);
    float si, co;
    __sincosf(rad, &si, &co);
    float txs = dx[b];
    float tys = dy[b];

    // tile-corner sample coords (uniform across block)
    float xo0 = (float)X0 - cx - txs;
    float xo1 = (float)(X0 + TILE_W - 1) - cx - txs;
    float yo0 = (float)Y0 - cy - tys;
    float yo1 = (float)(Y0 + TILE_H - 1) - cy - tys;

    float xsA = co * xo0 + si * yo0 + cx;
    float xsB = co * xo1 + si * yo0 + cx;
    float xsC = co * xo0 + si * yo1 + cx;
    float xsD = co * xo1 + si * yo1 + cx;
    float ysA = -si * xo0 + co * yo0 + cy;
    float ysB = -si * xo1 + co * yo0 + cy;
    float ysC = -si * xo0 + co * yo1 + cy;
    float ysD = -si * xo1 + co * yo1 + cy;

    float xsmin = fminf(fminf(xsA, xsB), fminf(xsC, xsD));
    float xsmax = fmaxf(fmaxf(xsA, xsB), fmaxf(xsC, xsD));
    float ysmin = fminf(fminf(ysA, ysB), fminf(ysC, ysD));
    float ysmax = fmaxf(fmaxf(ysA, ysB), fmaxf(ysC, ysD));

    int ximin = (int)floorf(xsmin) - 1;
    int yimin = (int)floorf(ysmin) - 1;
    int LH = (int)floorf(ysmax) + 2 - yimin + 1;  // <= 43
    LH = min(LH, LH_MAX);

    // block-uniform interior test (full staged window in-bounds)
    bool interior = (ximin >= 0) && (yimin >= 0) &&
                    (ximin + LW_STRIDE <= WW) && (yimin + LH <= HH);

    const float* imgb = x + (size_t)b * CC * HW;

    int nelem = LH * LW_STRIDE;
    if (interior) {
        // ---- fast staging: no clamps ----
        const float* srcb = imgb + yimin * WW + ximin;
        for (int i = tid; i < nelem; i += 512) {
            int y  = i / LW_STRIDE;
            int xL = i - y * LW_STRIDE;
            const float* src = srcb + y * WW + xL;
            ldsT[i] = pck(src[0], src[HW], src[2 * HW]);
        }
    } else {
        // ---- clamped staging ----
        for (int i = tid; i < nelem; i += 512) {
            int y  = i / LW_STRIDE;
            int xL = i - y * LW_STRIDE;
            int gy = min(max(yimin + y, 0), HH - 1);
            int gx = min(max(ximin + xL, 0), WW - 1);
            const float* src = imgb + gy * WW + gx;
            ldsT[i] = pck(src[0], src[HW], src[2 * HW]);
        }
    }
    __syncthreads();

    // ---- gather from LDS ----
    int x_out = X0 + tx;
    float xo = (float)x_out - cx - txs;
    float yo = (float)(Y0 + tyl) - cy - tys;

    float xs =  co * xo + si * yo + cx;
    float ys = -si * xo + co * yo + cy;
    const float dxs = 8.0f * si;
    const float dys = 8.0f * co;

    float* outb = out + (size_t)b * CC * HW + (size_t)Y0 * WW + x_out;

    if (interior) {
        #pragma unroll
        for (int r = 0; r < TILE_H / 8; ++r) {
            float x0f = floorf(xs);
            float y0f = floorf(ys);
            float wx = xs - x0f;
            float wy = ys - y0f;
            int base = ((int)y0f - yimin) * LW_STRIDE + ((int)x0f - ximin);

            uint2 q00 = ldsT[base];
            uint2 q01 = ldsT[base + 1];
            uint2 q10 = ldsT[base + LW_STRIDE];
            uint2 q11 = ldsT[base + LW_STRIDE + 1];

            float3 a00 = unp(q00);
            float3 a01 = unp(q01);
            float3 a10 = unp(q10);
            float3 a11 = unp(q11);

            float* o = outb + (size_t)(tyl + r * 8) * WW;
            {
                float top = a00.x + wx * (a01.x - a00.x);
                float bot = a10.x + wx * (a11.x - a10.x);
                float v = top + wy * (bot - top);
                __builtin_nontemporal_store(fminf(fmaxf(v, 0.0f), 1.0f), o);
            }
            {
                float top = a00.y + wx * (a01.y - a00.y);
                float bot = a10.y + wx * (a11.y - a10.y);
                float v = top + wy * (bot - top);
                __builtin_nontemporal_store(fminf(fmaxf(v, 0.0f), 1.0f), o + HW);
            }
            {
                float top = a00.z + wx * (a01.z - a00.z);
                float bot = a10.z + wx * (a11.z - a10.z);
                float v = top + wy * (bot - top);
                __builtin_nontemporal_store(fminf(fmaxf(v, 0.0f), 1.0f), o + 2 * HW);
            }
            xs += dxs;
            ys += dys;
        }
    } else {
        #pragma unroll
        for (int r = 0; r < TILE_H / 8; ++r) {
            float x0f = floorf(xs);
            float y0f = floorf(ys);
            float wx = xs - x0f;
            float wy = ys - y0f;
            int x0 = (int)x0f;
            int y0 = (int)y0f;
            int x1 = x0 + 1;
            int y1 = y0 + 1;

            float vx0 = (x0 >= 0 && x0 < WW) ? 1.0f : 0.0f;
            float vx1 = (x1 >= 0 && x1 < WW) ? 1.0f : 0.0f;
            float vy0 = (y0 >= 0 && y0 < HH) ? 1.0f : 0.0f;
            float vy1 = (y1 >= 0 && y1 < HH) ? 1.0f : 0.0f;

            float w00 = (1.0f - wx) * (1.0f - wy) * vx0 * vy0;
            float w01 = wx * (1.0f - wy) * vx1 * vy0;
            float w10 = (1.0f - wx) * wy * vx0 * vy1;
            float w11 = wx * wy * vx1 * vy1;

            int base = (y0 - yimin) * LW_STRIDE + (x0 - ximin);

            uint2 q00 = ldsT[base];
            uint2 q01 = ldsT[base + 1];
            uint2 q10 = ldsT[base + LW_STRIDE];
            uint2 q11 = ldsT[base + LW_STRIDE + 1];

            float3 a00 = unp(q00);
            float3 a01 = unp(q01);
            float3 a10 = unp(q10);
            float3 a11 = unp(q11);

            float* o = outb + (size_t)(tyl + r * 8) * WW;
            {
                float v = a00.x * w00 + a01.x * w01 + a10.x * w10 + a11.x * w11;
                __builtin_nontemporal_store(fminf(fmaxf(v, 0.0f), 1.0f), o);
            }
            {
                float v = a00.y * w00 + a01.y * w01 + a10.y * w10 + a11.y * w11;
                __builtin_nontemporal_store(fminf(fmaxf(v, 0.0f), 1.0f), o + HW);
            }
            {
                float v = a00.z * w00 + a01.z * w01 + a10.z * w10 + a11.z * w11;
                __builtin_nontemporal_store(fminf(fmaxf(v, 0.0f), 1.0f), o + 2 * HW);
            }
            xs += dxs;
            ys += dys;
        }
    }
}

extern "C" void kernel_launch(void* const* d_in, const int* in_sizes, int n_in,
                              void* d_out, int out_size, void* d_ws, size_t ws_size,
                              hipStream_t stream) {
    const float* x      = (const float*)d_in[0];
    const float* angles = (const float*)d_in[1];
    const float* dx     = (const float*)d_in[2];
    const float* dy     = (const float*)d_in[3];
    float* out = (float*)d_out;

    GeometricAugment_kernel<<<NBLOCKS, 512, 0, stream>>>(x, angles, dx, dy, out);
}

// Round 10
// 40.243 us; speedup vs baseline: 1.1204x; 1.1204x over previous
//
#include <hip/hip_runtime.h>
#include <hip/hip_bf16.h>
#include <math.h>

#define BB 64
#define CC 3
#define HH 384
#define WW 384
#define HW (HH * WW)

// Each block: 64x24 output tile of one image (3 channels), staged via LDS.
// 512 threads = 64(x) x 8(y); each thread does 3 rows (stride 8).
// R9 = R5 structure (best: 39.8us) with PLAIN stores instead of nontemporal:
// input(113MB)+output(110MB) < 256MB L3 -> replay steady-state writes absorbed.
#define TILE_W 64
#define TILE_H 24
#define TX_TILES (WW / TILE_W)                 // 6
#define TY_TILES (HH / TILE_H)                 // 16
#define TILES_PER_IMG (TX_TILES * TY_TILES)    // 96
#define NBLOCKS (BB * TILES_PER_IMG)           // 6144 (divisible by 8)

// Rotated bbox of 64x24 at <=15deg: LW <= 71, LH <= 43.
#define LW_STRIDE 71      // odd -> rows shift banks by 7
#define LH_MAX 43
#define LCH (LH_MAX * LW_STRIDE)
// LDS = 3 * 43 * 71 * 4 = 36636 B -> 4 blocks/CU x 8 waves = 32 waves (100%)

__global__ __launch_bounds__(512, 8) void GeometricAugment_kernel(
    const float* __restrict__ x,
    const float* __restrict__ angles,
    const float* __restrict__ dx,
    const float* __restrict__ dy,
    float* __restrict__ out) {

    __shared__ float lds[CC * LCH];

    // XCD-chunked bijective swizzle (6144 % 8 == 0)
    int bid = blockIdx.x;
    int swz = (bid & 7) * (NBLOCKS / 8) + (bid >> 3);

    int b   = swz / TILES_PER_IMG;
    int t   = swz - b * TILES_PER_IMG;
    int tyb = t / TX_TILES;
    int txb = t - tyb * TX_TILES;

    int tid = threadIdx.x;
    int tx  = tid & 63;   // 0..63
    int tyl = tid >> 6;   // 0..7

    const int X0 = txb * TILE_W;
    const int Y0 = tyb * TILE_H;

    const float cx = (WW - 1) * 0.5f;
    const float cy = (HH - 1) * 0.5f;

    float rad = angles[b] * (float)(M_PI / 180.0);
    float si, co;
    __sincosf(rad, &si, &co);
    float txs = dx[b];
    float tys = dy[b];

    // tile-corner sample coords (uniform across block)
    float xo0 = (float)X0 - cx - txs;
    float xo1 = (float)(X0 + TILE_W - 1) - cx - txs;
    float yo0 = (float)Y0 - cy - tys;
    float yo1 = (float)(Y0 + TILE_H - 1) - cy - tys;

    float xsA = co * xo0 + si * yo0 + cx;
    float xsB = co * xo1 + si * yo0 + cx;
    float xsC = co * xo0 + si * yo1 + cx;
    float xsD = co * xo1 + si * yo1 + cx;
    float ysA = -si * xo0 + co * yo0 + cy;
    float ysB = -si * xo1 + co * yo0 + cy;
    float ysC = -si * xo0 + co * yo1 + cy;
    float ysD = -si * xo1 + co * yo1 + cy;

    float xsmin = fminf(fminf(xsA, xsB), fminf(xsC, xsD));
    float xsmax = fmaxf(fmaxf(xsA, xsB), fmaxf(xsC, xsD));
    float ysmin = fminf(fminf(ysA, ysB), fminf(ysC, ysD));
    float ysmax = fmaxf(fmaxf(ysA, ysB), fmaxf(ysC, ysD));

    int ximin = (int)floorf(xsmin) - 1;
    int yimin = (int)floorf(ysmin) - 1;
    int LH = (int)floorf(ysmax) + 2 - yimin + 1;  // <= 43
    LH = min(LH, LH_MAX);

    // block-uniform interior test (full staged window in-bounds)
    bool interior = (ximin >= 0) && (yimin >= 0) &&
                    (ximin + LW_STRIDE <= WW) && (yimin + LH <= HH);

    const float* imgb = x + (size_t)b * CC * HW;

    int nelem = LH * LW_STRIDE;
    if (interior) {
        // ---- fast staging: no clamps ----
        const float* srcb = imgb + yimin * WW + ximin;
        for (int i = tid; i < nelem; i += 512) {
            int y  = i / LW_STRIDE;
            int xL = i - y * LW_STRIDE;
            const float* src = srcb + y * WW + xL;
            #pragma unroll
            for (int c = 0; c < CC; ++c)
                lds[c * LCH + i] = src[c * HW];
        }
    } else {
        // ---- clamped staging ----
        for (int i = tid; i < nelem; i += 512) {
            int y  = i / LW_STRIDE;
            int xL = i - y * LW_STRIDE;
            int gy = min(max(yimin + y, 0), HH - 1);
            int gx = min(max(ximin + xL, 0), WW - 1);
            const float* src = imgb + gy * WW + gx;
            #pragma unroll
            for (int c = 0; c < CC; ++c)
                lds[c * LCH + i] = src[c * HW];
        }
    }
    __syncthreads();

    // ---- gather from LDS ----
    int x_out = X0 + tx;
    float xo = (float)x_out - cx - txs;
    float yo = (float)(Y0 + tyl) - cy - tys;

    float xs =  co * xo + si * yo + cx;
    float ys = -si * xo + co * yo + cy;
    const float dxs = 8.0f * si;
    const float dys = 8.0f * co;

    float* outb = out + (size_t)b * CC * HW + (size_t)Y0 * WW + x_out;

    if (interior) {
        #pragma unroll
        for (int r = 0; r < TILE_H / 8; ++r) {
            float x0f = floorf(xs);
            float y0f = floorf(ys);
            float wx = xs - x0f;
            float wy = ys - y0f;
            int base = ((int)y0f - yimin) * LW_STRIDE + ((int)x0f - ximin);

            #pragma unroll
            for (int c = 0; c < CC; ++c) {
                const float* l = lds + c * LCH + base;
                float v00 = l[0];
                float v01 = l[1];
                float v10 = l[LW_STRIDE];
                float v11 = l[LW_STRIDE + 1];
                float top = v00 + wx * (v01 - v00);
                float bot = v10 + wx * (v11 - v10);
                float v = top + wy * (bot - top);
                v = fminf(fmaxf(v, 0.0f), 1.0f);
                outb[(size_t)c * HW + (size_t)(tyl + r * 8) * WW] = v;
            }
            xs += dxs;
            ys += dys;
        }
    } else {
        #pragma unroll
        for (int r = 0; r < TILE_H / 8; ++r) {
            float x0f = floorf(xs);
            float y0f = floorf(ys);
            float wx = xs - x0f;
            float wy = ys - y0f;
            int x0 = (int)x0f;
            int y0 = (int)y0f;
            int x1 = x0 + 1;
            int y1 = y0 + 1;

            float vx0 = (x0 >= 0 && x0 < WW) ? 1.0f : 0.0f;
            float vx1 = (x1 >= 0 && x1 < WW) ? 1.0f : 0.0f;
            float vy0 = (y0 >= 0 && y0 < HH) ? 1.0f : 0.0f;
            float vy1 = (y1 >= 0 && y1 < HH) ? 1.0f : 0.0f;

            float w00 = (1.0f - wx) * (1.0f - wy) * vx0 * vy0;
            float w01 = wx * (1.0f - wy) * vx1 * vy0;
            float w10 = (1.0f - wx) * wy * vx0 * vy1;
            float w11 = wx * wy * vx1 * vy1;

            int base = (y0 - yimin) * LW_STRIDE + (x0 - ximin);

            #pragma unroll
            for (int c = 0; c < CC; ++c) {
                const float* l = lds + c * LCH + base;
                float v00 = l[0];
                float v01 = l[1];
                float v10 = l[LW_STRIDE];
                float v11 = l[LW_STRIDE + 1];
                float v = v00 * w00 + v01 * w01 + v10 * w10 + v11 * w11;
                v = fminf(fmaxf(v, 0.0f), 1.0f);
                outb[(size_t)c * HW + (size_t)(tyl + r * 8) * WW] = v;
            }
            xs += dxs;
            ys += dys;
        }
    }
}

extern "C" void kernel_launch(void* const* d_in, const int* in_sizes, int n_in,
                              void* d_out, int out_size, void* d_ws, size_t ws_size,
                              hipStream_t stream) {
    const float* x      = (const float*)d_in[0];
    const float* angles = (const float*)d_in[1];
    const float* dx     = (const float*)d_in[2];
    const float* dy     = (const float*)d_in[3];
    float* out = (float*)d_out;

    GeometricAugment_kernel<<<NBLOCKS, 512, 0, stream>>>(x, angles, dx, dy, out);
}

// Round 11
// 39.776 us; speedup vs baseline: 1.1336x; 1.0118x over previous
//
#include <hip/hip_runtime.h>
#include <hip/hip_bf16.h>
#include <math.h>

#define BB 64
#define CC 3
#define HH 384
#define WW 384
#define HW (HH * WW)

// Each block: 64x24 output tile of one image (3 channels), staged via LDS.
// 512 threads = 64(x) x 8(y); each thread does 3 rows (stride 8).
// R10 = R5 + batched staging: fixed 6-iter unroll, all 18 loads issued
// back-to-back into regs (one vmcnt drain), then all ds_writes.
#define TILE_W 64
#define TILE_H 24
#define TX_TILES (WW / TILE_W)                 // 6
#define TY_TILES (HH / TILE_H)                 // 16
#define TILES_PER_IMG (TX_TILES * TY_TILES)    // 96
#define NBLOCKS (BB * TILES_PER_IMG)           // 6144 (divisible by 8)

// Rotated bbox of 64x24 at <=15deg: LW <= 71, LH <= 43.
#define LW_STRIDE 71      // odd -> rows shift banks by 7
#define LH_MAX 43
#define LCH (LH_MAX * LW_STRIDE)
#define NSTG 6            // ceil(43*71 / 512) = 6 staging iterations
// LDS = 3 * 43 * 71 * 4 = 36636 B -> 4 blocks/CU x 8 waves = 32 waves (100%)

__global__ __launch_bounds__(512, 8) void GeometricAugment_kernel(
    const float* __restrict__ x,
    const float* __restrict__ angles,
    const float* __restrict__ dx,
    const float* __restrict__ dy,
    float* __restrict__ out) {

    __shared__ float lds[CC * LCH];

    // XCD-chunked bijective swizzle (6144 % 8 == 0)
    int bid = blockIdx.x;
    int swz = (bid & 7) * (NBLOCKS / 8) + (bid >> 3);

    int b   = swz / TILES_PER_IMG;
    int t   = swz - b * TILES_PER_IMG;
    int tyb = t / TX_TILES;
    int txb = t - tyb * TX_TILES;

    int tid = threadIdx.x;
    int tx  = tid & 63;   // 0..63
    int tyl = tid >> 6;   // 0..7

    const int X0 = txb * TILE_W;
    const int Y0 = tyb * TILE_H;

    const float cx = (WW - 1) * 0.5f;
    const float cy = (HH - 1) * 0.5f;

    float rad = angles[b] * (float)(M_PI / 180.0);
    float si, co;
    __sincosf(rad, &si, &co);
    float txs = dx[b];
    float tys = dy[b];

    // tile-corner sample coords (uniform across block)
    float xo0 = (float)X0 - cx - txs;
    float xo1 = (float)(X0 + TILE_W - 1) - cx - txs;
    float yo0 = (float)Y0 - cy - tys;
    float yo1 = (float)(Y0 + TILE_H - 1) - cy - tys;

    float xsA = co * xo0 + si * yo0 + cx;
    float xsB = co * xo1 + si * yo0 + cx;
    float xsC = co * xo0 + si * yo1 + cx;
    float xsD = co * xo1 + si * yo1 + cx;
    float ysA = -si * xo0 + co * yo0 + cy;
    float ysB = -si * xo1 + co * yo0 + cy;
    float ysC = -si * xo0 + co * yo1 + cy;
    float ysD = -si * xo1 + co * yo1 + cy;

    float xsmin = fminf(fminf(xsA, xsB), fminf(xsC, xsD));
    float xsmax = fmaxf(fmaxf(xsA, xsB), fmaxf(xsC, xsD));
    float ysmin = fminf(fminf(ysA, ysB), fminf(ysC, ysD));
    float ysmax = fmaxf(fmaxf(ysA, ysB), fmaxf(ysC, ysD));

    int ximin = (int)floorf(xsmin) - 1;
    int yimin = (int)floorf(ysmin) - 1;
    int LH = (int)floorf(ysmax) + 2 - yimin + 1;  // <= 43
    LH = min(LH, LH_MAX);

    // block-uniform interior test (full staged window in-bounds)
    bool interior = (ximin >= 0) && (yimin >= 0) &&
                    (ximin + LW_STRIDE <= WW) && (yimin + LH <= HH);

    const float* imgb = x + (size_t)b * CC * HW;

    int nelem = LH * LW_STRIDE;   // <= 3053 <= NSTG*512

    // ---- stage bbox into LDS: issue-early / write-late ----
    float s0[NSTG], s1[NSTG], s2[NSTG];
    if (interior) {
        const float* srcb = imgb + yimin * WW + ximin;
        #pragma unroll
        for (int k = 0; k < NSTG; ++k) {
            int i = tid + k * 512;
            if (i < nelem) {
                int y  = i / LW_STRIDE;
                int xL = i - y * LW_STRIDE;
                const float* src = srcb + y * WW + xL;
                s0[k] = src[0];
                s1[k] = src[HW];
                s2[k] = src[2 * HW];
            }
        }
    } else {
        #pragma unroll
        for (int k = 0; k < NSTG; ++k) {
            int i = tid + k * 512;
            if (i < nelem) {
                int y  = i / LW_STRIDE;
                int xL = i - y * LW_STRIDE;
                int gy = min(max(yimin + y, 0), HH - 1);
                int gx = min(max(ximin + xL, 0), WW - 1);
                const float* src = imgb + gy * WW + gx;
                s0[k] = src[0];
                s1[k] = src[HW];
                s2[k] = src[2 * HW];
            }
        }
    }
    #pragma unroll
    for (int k = 0; k < NSTG; ++k) {
        int i = tid + k * 512;
        if (i < nelem) {
            lds[i]           = s0[k];
            lds[LCH + i]     = s1[k];
            lds[2 * LCH + i] = s2[k];
        }
    }
    __syncthreads();

    // ---- gather from LDS ----
    int x_out = X0 + tx;
    float xo = (float)x_out - cx - txs;
    float yo = (float)(Y0 + tyl) - cy - tys;

    float xs =  co * xo + si * yo + cx;
    float ys = -si * xo + co * yo + cy;
    const float dxs = 8.0f * si;
    const float dys = 8.0f * co;

    float* outb = out + (size_t)b * CC * HW + (size_t)Y0 * WW + x_out;

    if (interior) {
        #pragma unroll
        for (int r = 0; r < TILE_H / 8; ++r) {
            float x0f = floorf(xs);
            float y0f = floorf(ys);
            float wx = xs - x0f;
            float wy = ys - y0f;
            int base = ((int)y0f - yimin) * LW_STRIDE + ((int)x0f - ximin);

            #pragma unroll
            for (int c = 0; c < CC; ++c) {
                const float* l = lds + c * LCH + base;
                float v00 = l[0];
                float v01 = l[1];
                float v10 = l[LW_STRIDE];
                float v11 = l[LW_STRIDE + 1];
                float top = v00 + wx * (v01 - v00);
                float bot = v10 + wx * (v11 - v10);
                float v = top + wy * (bot - top);
                v = fminf(fmaxf(v, 0.0f), 1.0f);
                __builtin_nontemporal_store(v, outb + (size_t)c * HW + (size_t)(tyl + r * 8) * WW);
            }
            xs += dxs;
            ys += dys;
        }
    } else {
        #pragma unroll
        for (int r = 0; r < TILE_H / 8; ++r) {
            float x0f = floorf(xs);
            float y0f = floorf(ys);
            float wx = xs - x0f;
            float wy = ys - y0f;
            int x0 = (int)x0f;
            int y0 = (int)y0f;
            int x1 = x0 + 1;
            int y1 = y0 + 1;

            float vx0 = (x0 >= 0 && x0 < WW) ? 1.0f : 0.0f;
            float vx1 = (x1 >= 0 && x1 < WW) ? 1.0f : 0.0f;
            float vy0 = (y0 >= 0 && y0 < HH) ? 1.0f : 0.0f;
            float vy1 = (y1 >= 0 && y1 < HH) ? 1.0f : 0.0f;

            float w00 = (1.0f - wx) * (1.0f - wy) * vx0 * vy0;
            float w01 = wx * (1.0f - wy) * vx1 * vy0;
            float w10 = (1.0f - wx) * wy * vx0 * vy1;
            float w11 = wx * wy * vx1 * vy1;

            int base = (y0 - yimin) * LW_STRIDE + (x0 - ximin);

            #pragma unroll
            for (int c = 0; c < CC; ++c) {
                const float* l = lds + c * LCH + base;
                float v00 = l[0];
                float v01 = l[1];
                float v10 = l[LW_STRIDE];
                float v11 = l[LW_STRIDE + 1];
                float v = v00 * w00 + v01 * w01 + v10 * w10 + v11 * w11;
                v = fminf(fmaxf(v, 0.0f), 1.0f);
                __builtin_nontemporal_store(v, outb + (size_t)c * HW + (size_t)(tyl + r * 8) * WW);
            }
            xs += dxs;
            ys += dys;
        }
    }
}

extern "C" void kernel_launch(void* const* d_in, const int* in_sizes, int n_in,
                              void* d_out, int out_size, void* d_ws, size_t ws_size,
                              hipStream_t stream) {
    const float* x      = (const float*)d_in[0];
    const float* angles = (const float*)d_in[1];
    const float* dx     = (const float*)d_in[2];
    const float* dy     = (const float*)d_in[3];
    float* out = (float*)d_out;

    GeometricAugment_kernel<<<NBLOCKS, 512, 0, stream>>>(x, angles, dx, dy, out);
}

// Round 12
// 38.913 us; speedup vs baseline: 1.1587x; 1.0222x over previous
//
#include <hip/hip_runtime.h>
#include <hip/hip_bf16.h>
#include <math.h>

#define BB 64
#define CC 3
#define HH 384
#define WW 384
#define HW (HH * WW)

// Each block: 64x48 output tile of one image (3 channels), staged via LDS.
// 1024 threads = 64(x) x 16(y); each thread does 3 rows (stride 16).
// Squarer tile -> halo ratio 1.93 (64x24) -> 1.68; half the blocks.
#define TILE_W 64
#define TILE_H 48
#define TX_TILES (WW / TILE_W)                 // 6
#define TY_TILES (HH / TILE_H)                 // 8
#define TILES_PER_IMG (TX_TILES * TY_TILES)    // 48
#define NBLOCKS (BB * TILES_PER_IMG)           // 3072 (divisible by 8)

// Rotated bbox of 64x48 at <=15deg:
//   x floor-span <= 63*cos15+47*sin15 = 73.0 -> 74; +4 -> LW <= 78
//   y floor-span <= 63*sin15+47*cos15 = 61.7 -> 62; +4 -> LH <= 66
#define LW_STRIDE 79      // odd (>=78) -> rows shift banks by 15
#define LH_MAX 66
#define LCH (LH_MAX * LW_STRIDE)
#define NSTG 6            // ceil(66*79 / 1024) = 6 staging iterations
// LDS = 3 * 66 * 79 * 4 = 62568 B -> 2 blocks/CU x 16 waves = 32 waves (100%)

__global__ __launch_bounds__(1024, 8) void GeometricAugment_kernel(
    const float* __restrict__ x,
    const float* __restrict__ angles,
    const float* __restrict__ dx,
    const float* __restrict__ dy,
    float* __restrict__ out) {

    __shared__ float lds[CC * LCH];

    // XCD-chunked bijective swizzle (3072 % 8 == 0)
    int bid = blockIdx.x;
    int swz = (bid & 7) * (NBLOCKS / 8) + (bid >> 3);

    int b   = swz / TILES_PER_IMG;
    int t   = swz - b * TILES_PER_IMG;
    int tyb = t / TX_TILES;
    int txb = t - tyb * TX_TILES;

    int tid = threadIdx.x;
    int tx  = tid & 63;   // 0..63
    int tyl = tid >> 6;   // 0..15

    const int X0 = txb * TILE_W;
    const int Y0 = tyb * TILE_H;

    const float cx = (WW - 1) * 0.5f;
    const float cy = (HH - 1) * 0.5f;

    float rad = angles[b] * (float)(M_PI / 180.0);
    float si, co;
    __sincosf(rad, &si, &co);
    float txs = dx[b];
    float tys = dy[b];

    // tile-corner sample coords (uniform across block)
    float xo0 = (float)X0 - cx - txs;
    float xo1 = (float)(X0 + TILE_W - 1) - cx - txs;
    float yo0 = (float)Y0 - cy - tys;
    float yo1 = (float)(Y0 + TILE_H - 1) - cy - tys;

    float xsA = co * xo0 + si * yo0 + cx;
    float xsB = co * xo1 + si * yo0 + cx;
    float xsC = co * xo0 + si * yo1 + cx;
    float xsD = co * xo1 + si * yo1 + cx;
    float ysA = -si * xo0 + co * yo0 + cy;
    float ysB = -si * xo1 + co * yo0 + cy;
    float ysC = -si * xo0 + co * yo1 + cy;
    float ysD = -si * xo1 + co * yo1 + cy;

    float xsmin = fminf(fminf(xsA, xsB), fminf(xsC, xsD));
    float xsmax = fmaxf(fmaxf(xsA, xsB), fmaxf(xsC, xsD));
    float ysmin = fminf(fminf(ysA, ysB), fminf(ysC, ysD));
    float ysmax = fmaxf(fmaxf(ysA, ysB), fmaxf(ysC, ysD));

    int ximin = (int)floorf(xsmin) - 1;
    int yimin = (int)floorf(ysmin) - 1;
    int LH = (int)floorf(ysmax) + 2 - yimin + 1;  // <= 66
    LH = min(LH, LH_MAX);

    // block-uniform interior test (full staged window in-bounds)
    bool interior = (ximin >= 0) && (yimin >= 0) &&
                    (ximin + LW_STRIDE <= WW) && (yimin + LH <= HH);

    const float* imgb = x + (size_t)b * CC * HW;

    int nelem = LH * LW_STRIDE;   // <= 5214 <= NSTG*1024

    // ---- stage bbox into LDS: issue-early / write-late ----
    float s0[NSTG], s1[NSTG], s2[NSTG];
    if (interior) {
        const float* srcb = imgb + yimin * WW + ximin;
        #pragma unroll
        for (int k = 0; k < NSTG; ++k) {
            int i = tid + k * 1024;
            if (i < nelem) {
                int y  = i / LW_STRIDE;
                int xL = i - y * LW_STRIDE;
                const float* src = srcb + y * WW + xL;
                s0[k] = src[0];
                s1[k] = src[HW];
                s2[k] = src[2 * HW];
            }
        }
    } else {
        #pragma unroll
        for (int k = 0; k < NSTG; ++k) {
            int i = tid + k * 1024;
            if (i < nelem) {
                int y  = i / LW_STRIDE;
                int xL = i - y * LW_STRIDE;
                int gy = min(max(yimin + y, 0), HH - 1);
                int gx = min(max(ximin + xL, 0), WW - 1);
                const float* src = imgb + gy * WW + gx;
                s0[k] = src[0];
                s1[k] = src[HW];
                s2[k] = src[2 * HW];
            }
        }
    }
    #pragma unroll
    for (int k = 0; k < NSTG; ++k) {
        int i = tid + k * 1024;
        if (i < nelem) {
            lds[i]           = s0[k];
            lds[LCH + i]     = s1[k];
            lds[2 * LCH + i] = s2[k];
        }
    }
    __syncthreads();

    // ---- gather from LDS ----
    int x_out = X0 + tx;
    float xo = (float)x_out - cx - txs;
    float yo = (float)(Y0 + tyl) - cy - tys;

    float xs =  co * xo + si * yo + cx;
    float ys = -si * xo + co * yo + cy;
    const float dxs = 16.0f * si;
    const float dys = 16.0f * co;

    float* outb = out + (size_t)b * CC * HW + (size_t)Y0 * WW + x_out;

    if (interior) {
        #pragma unroll
        for (int r = 0; r < TILE_H / 16; ++r) {
            float x0f = floorf(xs);
            float y0f = floorf(ys);
            float wx = xs - x0f;
            float wy = ys - y0f;
            int base = ((int)y0f - yimin) * LW_STRIDE + ((int)x0f - ximin);

            #pragma unroll
            for (int c = 0; c < CC; ++c) {
                const float* l = lds + c * LCH + base;
                float v00 = l[0];
                float v01 = l[1];
                float v10 = l[LW_STRIDE];
                float v11 = l[LW_STRIDE + 1];
                float top = v00 + wx * (v01 - v00);
                float bot = v10 + wx * (v11 - v10);
                float v = top + wy * (bot - top);
                v = fminf(fmaxf(v, 0.0f), 1.0f);
                __builtin_nontemporal_store(v, outb + (size_t)c * HW + (size_t)(tyl + r * 16) * WW);
            }
            xs += dxs;
            ys += dys;
        }
    } else {
        #pragma unroll
        for (int r = 0; r < TILE_H / 16; ++r) {
            float x0f = floorf(xs);
            float y0f = floorf(ys);
            float wx = xs - x0f;
            float wy = ys - y0f;
            int x0 = (int)x0f;
            int y0 = (int)y0f;
            int x1 = x0 + 1;
            int y1 = y0 + 1;

            float vx0 = (x0 >= 0 && x0 < WW) ? 1.0f : 0.0f;
            float vx1 = (x1 >= 0 && x1 < WW) ? 1.0f : 0.0f;
            float vy0 = (y0 >= 0 && y0 < HH) ? 1.0f : 0.0f;
            float vy1 = (y1 >= 0 && y1 < HH) ? 1.0f : 0.0f;

            float w00 = (1.0f - wx) * (1.0f - wy) * vx0 * vy0;
            float w01 = wx * (1.0f - wy) * vx1 * vy0;
            float w10 = (1.0f - wx) * wy * vx0 * vy1;
            float w11 = wx * wy * vx1 * vy1;

            int base = (y0 - yimin) * LW_STRIDE + (x0 - ximin);

            #pragma unroll
            for (int c = 0; c < CC; ++c) {
                const float* l = lds + c * LCH + base;
                float v00 = l[0];
                float v01 = l[1];
                float v10 = l[LW_STRIDE];
                float v11 = l[LW_STRIDE + 1];
                float v = v00 * w00 + v01 * w01 + v10 * w10 + v11 * w11;
                v = fminf(fmaxf(v, 0.0f), 1.0f);
                __builtin_nontemporal_store(v, outb + (size_t)c * HW + (size_t)(tyl + r * 16) * WW);
            }
            xs += dxs;
            ys += dys;
        }
    }
}

extern "C" void kernel_launch(void* const* d_in, const int* in_sizes, int n_in,
                              void* d_out, int out_size, void* d_ws, size_t ws_size,
                              hipStream_t stream) {
    const float* x      = (const float*)d_in[0];
    const float* angles = (const float*)d_in[1];
    const float* dx     = (const float*)d_in[2];
    const float* dy     = (const float*)d_in[3];
    float* out = (float*)d_out;

    GeometricAugment_kernel<<<NBLOCKS, 1024, 0, stream>>>(x, angles, dx, dy, out);
}